// Round 5
// baseline (403.153 us; speedup 1.0000x reference)
//
#include <hip/hip_runtime.h>
#include <hip/hip_bf16.h>
#include <hip/hip_fp16.h>
#include <math.h>

// MOSDecoder round 11:
//  - Decoder GEMM back on the r6 skeleton (128x128, 16x16x128 MX-fp8, 2
//    barriers/kstep) with three targeted LDS-pipe fixes:
//    (a) REGION LDS layout: each 16B k-half of each fragment is a 1KB region
//        [region][lane*16B] == global_load_lds native dest order; fragment
//        read = 2x ds_read_b128 at r*1024+lane*16 (canonical contiguous,
//        conflict-free) + const +1024 offset. No XOR swizzle, no repack addr
//        math. (r10's lane*32 stride was a 4-bank-group conflict: 1024
//        conflict-cyc/block measured in every LDS variant.)
//    (b) DPP row-reduce (v_add row_shr 1/2/4/8, VALU pipe) replaces the
//        epilogue __shfl_xor (256 wave ds_bpermutes/block on the LDS pipe).
//        Sum lands in lane 15 of each 16-lane row.
//    (c) single 32KB buffer -> 4-5 blocks/CU (was 2 @64KB) for cross-block
//        pipe overlap; r8 proved intra-block dbuf adds nothing.
//  - prep / latent_gemm / combine / grid / XCD map / math unchanged.

#define D_ 512
#define E_ 4
#define V_ 32000
#define L_ 1024
#define AROWS (L_ * E_)   // 4096

#define SA_ 0x7D7D7D7D    // e8m0 2^-2 (latent stored x4)
#define SB_ 0x7B7B7B7B    // e8m0 2^-4 (W_dec stored x16)

typedef __attribute__((ext_vector_type(8))) short s16x8;
typedef __attribute__((ext_vector_type(4))) float f32x4;
typedef __attribute__((ext_vector_type(2))) float f32x2;
typedef __attribute__((ext_vector_type(4))) int i32x4;
typedef __attribute__((ext_vector_type(8))) int i32x8;
typedef __attribute__((ext_vector_type(4))) unsigned int u32x4;
typedef const __attribute__((address_space(1))) char* gp1_t;
typedef __attribute__((address_space(3))) char* lp3_t;

__device__ __forceinline__ void gload_lds16(const void* g, void* l) {
  __builtin_amdgcn_global_load_lds((gp1_t)g, (lp3_t)l, 16, 0, 0);
}

// sum across each 16-lane row via DPP (VALU pipe, no LDS). Result in lane 15
// of each row (bound_ctrl=1 -> OOB contributes 0; old=0 covers either way).
__device__ __forceinline__ float dpp_row16_sum(float x) {
  int t;
  t = __builtin_amdgcn_update_dpp(0, __float_as_int(x), 0x111, 0xF, 0xF, true);
  x += __int_as_float(t);
  t = __builtin_amdgcn_update_dpp(0, __float_as_int(x), 0x112, 0xF, 0xF, true);
  x += __int_as_float(t);
  t = __builtin_amdgcn_update_dpp(0, __float_as_int(x), 0x114, 0xF, 0xF, true);
  x += __int_as_float(t);
  t = __builtin_amdgcn_update_dpp(0, __float_as_int(x), 0x118, 0xF, 0xF, true);
  x += __int_as_float(t);
  return x;
}

// ================= fused prep =================
// [0,8000)      tcvt W_dec [512][32000] -> fp8 WdecT8 [32000][512] (x16)
// [8000,9024)   tcvt W_latent -> bf16 WlatT [2048][512]
// [9024,9536)   cvt hs -> bf16
// [9536,9792)   prior log-softmax
// [9792,9808)   zero S
#define PREP_DEC  8000
#define PREP_LAT  (PREP_DEC + 1024)
#define PREP_CVT  (PREP_LAT + 512)
#define PREP_PRI  (PREP_CVT + 256)
#define PREP_TOT  (PREP_PRI + 16)

__global__ __launch_bounds__(256) void prep_kernel(
    const float* __restrict__ hs, const float* __restrict__ W_prior,
    const float* __restrict__ b_prior, const float* __restrict__ W_latent,
    const float* __restrict__ W_dec,
    __hip_bfloat16* __restrict__ hs_bf, __hip_bfloat16* __restrict__ WlatT,
    unsigned char* __restrict__ WdecT8, float* __restrict__ log_coef,
    float* __restrict__ S) {
  __shared__ float tileS[64 * 33];
  const int b = blockIdx.x;
  const int tid = threadIdx.x;

  if (b < PREP_DEC) {
    // W_dec [512][32000] -> WdecT8 [32000][512]; tile 64 d-rows x 32 v-cols.
    const int vb = (b % 1000) * 32;
    const int db = (b / 1000) * 64;
    {
      const int r = tid >> 2, c0 = (tid & 3) * 8;
      const float* src = W_dec + (size_t)(db + r) * V_ + vb + c0;
      float4 a0 = *(const float4*)src;
      float4 a1 = *(const float4*)(src + 4);
      float* t = &tileS[r * 33 + c0];
      t[0] = a0.x; t[1] = a0.y; t[2] = a0.z; t[3] = a0.w;
      t[4] = a1.x; t[5] = a1.y; t[6] = a1.z; t[7] = a1.w;
    }
    __syncthreads();
    {
      const int vr = tid >> 3, d0 = (tid & 7) * 8;
      float t8[8];
      #pragma unroll
      for (int j = 0; j < 8; ++j) t8[j] = tileS[(d0 + j) * 33 + vr] * 16.f;
      unsigned int u0 = 0, u1 = 0;
      u0 = __builtin_amdgcn_cvt_pk_fp8_f32(t8[0], t8[1], u0, false);
      u0 = __builtin_amdgcn_cvt_pk_fp8_f32(t8[2], t8[3], u0, true);
      u1 = __builtin_amdgcn_cvt_pk_fp8_f32(t8[4], t8[5], u1, false);
      u1 = __builtin_amdgcn_cvt_pk_fp8_f32(t8[6], t8[7], u1, true);
      uint2 uu = {u0, u1};
      *(uint2*)&WdecT8[(size_t)(vb + vr) * D_ + db + d0] = uu;
    }
  } else if (b < PREP_LAT) {
    const int bb = b - PREP_DEC;
    const int cb = (bb & 63) * 32, rb = (bb >> 6) * 32;
    const int C = E_ * D_, R = D_;
    const int tx = tid & 31, ty = tid >> 5;  // 32x8
    #pragma unroll
    for (int j = 0; j < 32; j += 8)
      tileS[(ty + j) * 33 + tx] = W_latent[(size_t)(rb + ty + j) * C + cb + tx];
    __syncthreads();
    #pragma unroll
    for (int j = 0; j < 32; j += 8)
      WlatT[(size_t)(cb + ty + j) * R + rb + tx] = __float2bfloat16(tileS[tx * 33 + ty + j]);
  } else if (b < PREP_CVT) {
    int i = ((b - PREP_LAT) * 256 + tid) * 4;
    float4 v = *(const float4*)(hs + i);
    hs_bf[i + 0] = __float2bfloat16(v.x);
    hs_bf[i + 1] = __float2bfloat16(v.y);
    hs_bf[i + 2] = __float2bfloat16(v.z);
    hs_bf[i + 3] = __float2bfloat16(v.w);
  } else if (b < PREP_PRI) {
    int t = (b - PREP_CVT) * 4 + (tid >> 6);
    int lane = tid & 63;
    float a0 = 0.f, a1 = 0.f, a2 = 0.f, a3 = 0.f;
    for (int d = lane; d < D_; d += 64) {
      float h = hs[t * D_ + d];
      float4 w = ((const float4*)W_prior)[d];
      a0 += h * w.x; a1 += h * w.y; a2 += h * w.z; a3 += h * w.w;
    }
    #pragma unroll
    for (int off = 32; off > 0; off >>= 1) {
      a0 += __shfl_xor(a0, off);
      a1 += __shfl_xor(a1, off);
      a2 += __shfl_xor(a2, off);
      a3 += __shfl_xor(a3, off);
    }
    a0 += b_prior[0]; a1 += b_prior[1]; a2 += b_prior[2]; a3 += b_prior[3];
    float mx = fmaxf(fmaxf(a0, a1), fmaxf(a2, a3));
    float ls = mx + logf(expf(a0 - mx) + expf(a1 - mx) + expf(a2 - mx) + expf(a3 - mx));
    if (lane == 0) {
      log_coef[t * 4 + 0] = a0 - ls;
      log_coef[t * 4 + 1] = a1 - ls;
      log_coef[t * 4 + 2] = a2 - ls;
      log_coef[t * 4 + 3] = a3 - ls;
    }
  } else {
    S[(b - PREP_PRI) * 256 + tid] = 0.f;
  }
}

// ---- q = exp(log_coef)/S (fallback path only) ----
__global__ void qk_kernel(const float* __restrict__ log_coef, const float* __restrict__ S,
                          float* __restrict__ q) {
  int i = blockIdx.x * blockDim.x + threadIdx.x;
  if (i < AROWS) q[i] = __expf(log_coef[i]) / S[i];
}

// ---- latent = fp8(4*tanh(hs @ W_latent + b)) -> [L][E*D] == [4096][512] ----
__global__ __launch_bounds__(256, 2) void latent_gemm(
    const __hip_bfloat16* __restrict__ Abf, const __hip_bfloat16* __restrict__ BT,
    const float* __restrict__ b_latent, unsigned char* __restrict__ latent8) {
  __shared__ short As[128 * 32];
  __shared__ short Bs[128 * 32];
  const int tid = threadIdx.x;
  const int wave = tid >> 6, lane = tid & 63;
  const int wm = wave >> 1, wn = wave & 1;
  const int m0 = blockIdx.y * 128;
  const int n0 = blockIdx.x * 128;
  const int lrow = lane & 15;
  const int kgrp = lane >> 4;
  const int srow = wave * 16 + (lane >> 2);
  const int scol = (lane & 3) * 8;

  f32x4 acc[4][4];
  #pragma unroll
  for (int mt = 0; mt < 4; ++mt)
    #pragma unroll
    for (int nt = 0; nt < 4; ++nt) acc[mt][nt] = f32x4{0.f, 0.f, 0.f, 0.f};

  for (int kt = 0; kt < 16; ++kt) {
    const int k0 = kt * 32;
    #pragma unroll
    for (int j = 0; j < 2; ++j) {
      const int row = j * 64 + srow;
      gload_lds16(Abf + (size_t)(m0 + row) * D_ + k0 + scol, &As[(j * 256 + wave * 64) * 8]);
      gload_lds16(BT + (size_t)(n0 + row) * D_ + k0 + scol, &Bs[(j * 256 + wave * 64) * 8]);
    }
    __syncthreads();
    s16x8 af[4], bfr[4];
    #pragma unroll
    for (int mt = 0; mt < 4; ++mt) af[mt] = *(const s16x8*)&As[(wm * 64 + mt * 16 + lrow) * 32 + kgrp * 8];
    #pragma unroll
    for (int nt = 0; nt < 4; ++nt) bfr[nt] = *(const s16x8*)&Bs[(wn * 64 + nt * 16 + lrow) * 32 + kgrp * 8];
    #pragma unroll
    for (int mt = 0; mt < 4; ++mt)
      #pragma unroll
      for (int nt = 0; nt < 4; ++nt)
        acc[mt][nt] = __builtin_amdgcn_mfma_f32_16x16x32_bf16(af[mt], bfr[nt], acc[mt][nt], 0, 0, 0);
    __syncthreads();
  }

  float blat[4];
  #pragma unroll
  for (int nt = 0; nt < 4; ++nt) blat[nt] = b_latent[n0 + wn * 64 + nt * 16 + lrow];
  #pragma unroll
  for (int mt = 0; mt < 4; ++mt)
    #pragma unroll
    for (int r = 0; r < 4; ++r) {
      const int row = m0 + wm * 64 + mt * 16 + kgrp * 4 + r;  // token
      #pragma unroll
      for (int nt = 0; nt < 4; ++nt) {
        const int col = n0 + wn * 64 + nt * 16 + lrow;
        float v = tanhf(acc[mt][nt][r] + blat[nt]) * 4.f;     // x4: e4m3 + HW scale 2^-2
        int u = __builtin_amdgcn_cvt_pk_fp8_f32(v, v, 0, false);
        latent8[(size_t)row * (E_ * D_) + col] = (unsigned char)(u & 0xff);
      }
    }
}

// ---- decoder GEMM (MX-fp8, 16x16x128), 128x128 tile, region LDS layout,
//      single 32KB buffer, 2 barriers/kstep, DPP epilogue reduce.
//      MODE 1: S only. MODE 2: out directly. MODE 3: S + p=exp packed fp8. ----
template <int MODE>
__global__ __launch_bounds__(256, 2) void mos_gemm(
    const unsigned char* __restrict__ A8,      // [4096][512] fp8 (x4), row = l*4+e
    const unsigned char* __restrict__ W8,      // [32000][512] fp8 (x16)
    const float* __restrict__ b_dec,
    const float* __restrict__ q,               // [4096] (MODE 2)
    float* __restrict__ S,                     // [4096] (MODE 1/3)
    float* __restrict__ out,                   // [1024][32000] (MODE 2)
    unsigned int* __restrict__ pbuf) {         // [1024][32000] (MODE 3)
  const int bid = blockIdx.x;
  const int xcd = bid & 7;
  const int idx = bid >> 3;
  const int mg = xcd >> 2;
  const int vg = xcd & 3;
  const int vt = vg * 63 + (idx >> 4);
  const int mtile = mg * 16 + (idx & 15);
  if (vt >= V_ / 128) return;
  const int m0 = mtile * 128;
  const int v0 = vt * 128;

  // Region layout: 16 A-regions + 16 B-regions of 1KB. Region r (g=r>>1 is the
  // 16-row fragment group, h=r&1 the 16B k-half): slot l holds
  // global[row = g*16 + (l&15)][kb + (l>>4)*32 + h*16]. Slot order == the
  // native global_load_lds dest order (base + lane*16).
  __shared__ __attribute__((aligned(16))) unsigned char As[16384];
  __shared__ __attribute__((aligned(16))) unsigned char Bs[16384];

  const int tid = threadIdx.x;
  const int wave = tid >> 6, lane = tid & 63;
  const int wm = wave >> 1, wn = wave & 1;
  const int lrow = lane & 15;
  const int kgrp = lane >> 4;

  // staging sources: thread (wave, lane) fills slot `lane` of regions
  // r = c*4 + wave, c = 0..3, for both A and B.
  const unsigned char* gA[4];
  const unsigned char* gB[4];
  #pragma unroll
  for (int c = 0; c < 4; ++c) {
    const int r = c * 4 + wave;
    const int row = (r >> 1) * 16 + lrow;
    const int kof = kgrp * 32 + (r & 1) * 16;
    gA[c] = A8 + (size_t)(m0 + row) * D_ + kof;
    gB[c] = W8 + (size_t)(v0 + row) * D_ + kof;
  }

  float bdec[4];
  #pragma unroll
  for (int nt = 0; nt < 4; ++nt) bdec[nt] = b_dec[v0 + wn * 64 + nt * 16 + lrow];

  f32x4 acc[4][4];
  #pragma unroll
  for (int mt = 0; mt < 4; ++mt)
    #pragma unroll
    for (int nt = 0; nt < 4; ++nt) acc[mt][nt] = f32x4{0.f, 0.f, 0.f, 0.f};

  #pragma unroll
  for (int kt = 0; kt < 4; ++kt) {
    const int kb = kt * 128;
    #pragma unroll
    for (int c = 0; c < 4; ++c) {
      gload_lds16(gA[c] + kb, &As[(c * 4 + wave) * 1024]);
      gload_lds16(gB[c] + kb, &Bs[(c * 4 + wave) * 1024]);
    }
    __syncthreads();
    i32x8 bf8[4];
    #pragma unroll
    for (int nt = 0; nt < 4; ++nt) {
      const int g = wn * 4 + nt;
      i32x4 lo = *(const i32x4*)&Bs[g * 2048 + lane * 16];
      i32x4 hi = *(const i32x4*)&Bs[g * 2048 + 1024 + lane * 16];
      bf8[nt] = __builtin_shufflevector(lo, hi, 0, 1, 2, 3, 4, 5, 6, 7);
    }
    __builtin_amdgcn_s_setprio(1);
    #pragma unroll
    for (int mt = 0; mt < 4; ++mt) {
      const int g = wm * 4 + mt;
      i32x4 lo = *(const i32x4*)&As[g * 2048 + lane * 16];
      i32x4 hi = *(const i32x4*)&As[g * 2048 + 1024 + lane * 16];
      i32x8 a = __builtin_shufflevector(lo, hi, 0, 1, 2, 3, 4, 5, 6, 7);
      #pragma unroll
      for (int nt = 0; nt < 4; ++nt)
        acc[mt][nt] = __builtin_amdgcn_mfma_scale_f32_16x16x128_f8f6f4(
            a, bf8[nt], acc[mt][nt], 0, 0, 0, SA_, 0, SB_);
    }
    __builtin_amdgcn_s_setprio(0);
    __syncthreads();
  }

  if constexpr (MODE == 1 || MODE == 3) {
    #pragma unroll
    for (int mt = 0; mt < 4; ++mt) {
      const int row4 = m0 + wm * 64 + mt * 16 + kgrp * 4;
      const int token = row4 >> 2;
      float p0 = 0.f, p1 = 0.f, p2 = 0.f, p3 = 0.f;
      #pragma unroll
      for (int nt = 0; nt < 4; ++nt) {
        float e0 = __expf(acc[mt][nt][0] + bdec[nt]);
        float e1 = __expf(acc[mt][nt][1] + bdec[nt]);
        float e2 = __expf(acc[mt][nt][2] + bdec[nt]);
        float e3 = __expf(acc[mt][nt][3] + bdec[nt]);
        p0 += e0; p1 += e1; p2 += e2; p3 += e3;
        if constexpr (MODE == 3) {
          const int v = v0 + wn * 64 + nt * 16 + lrow;
          int u = 0;
          u = __builtin_amdgcn_cvt_pk_fp8_f32(e0, e1, u, false);
          u = __builtin_amdgcn_cvt_pk_fp8_f32(e2, e3, u, true);
          __builtin_nontemporal_store((unsigned int)u, &pbuf[(size_t)token * V_ + v]);
        }
      }
      // DPP row16 reduce (VALU pipe); row sum lands in lane 15 of each row.
      p0 = dpp_row16_sum(p0);
      p1 = dpp_row16_sum(p1);
      p2 = dpp_row16_sum(p2);
      p3 = dpp_row16_sum(p3);
      if (lrow == 15) {
        atomicAdd(&S[row4 + 0], p0);
        atomicAdd(&S[row4 + 1], p1);
        atomicAdd(&S[row4 + 2], p2);
        atomicAdd(&S[row4 + 3], p3);
      }
    }
  } else {  // MODE == 2
    #pragma unroll
    for (int mt = 0; mt < 4; ++mt) {
      const int row4 = m0 + wm * 64 + mt * 16 + kgrp * 4;
      const float4 qv = *(const float4*)&q[row4];
      const int token = row4 >> 2;
      #pragma unroll
      for (int nt = 0; nt < 4; ++nt) {
        float v = qv.x * __expf(acc[mt][nt][0] + bdec[nt]) +
                  qv.y * __expf(acc[mt][nt][1] + bdec[nt]) +
                  qv.z * __expf(acc[mt][nt][2] + bdec[nt]) +
                  qv.w * __expf(acc[mt][nt][3] + bdec[nt]);
        out[(size_t)token * V_ + v0 + wn * 64 + nt * 16 + lrow] = __logf(v);
      }
    }
  }
}

// ---- combine: out[t][v] = log(sum_e q_e * p8[t][v][e]) ----
__global__ __launch_bounds__(256) void combine_kernel(
    const unsigned int* __restrict__ pbuf,
    const float* __restrict__ lc, const float* __restrict__ S,
    float* __restrict__ out) {
  const int t = blockIdx.y;
  const int v = blockIdx.x * 1024 + threadIdx.x * 4;
  if (v >= V_) return;
  const float4 lcv = ((const float4*)lc)[t];
  const float4 Sv = ((const float4*)S)[t];
  const float q0 = __expf(lcv.x) / Sv.x;
  const float q1 = __expf(lcv.y) / Sv.y;
  const float q2 = __expf(lcv.z) / Sv.z;
  const float q3 = __expf(lcv.w) / Sv.w;
  u32x4 u = __builtin_nontemporal_load((const u32x4*)(pbuf + (size_t)t * V_ + v));
  float4 o;
  #pragma unroll
  for (int j = 0; j < 4; ++j) {
    unsigned int w = u[j];
    f32x2 lo = __builtin_amdgcn_cvt_pk_f32_fp8(w, false);
    f32x2 hi = __builtin_amdgcn_cvt_pk_f32_fp8(w, true);
    float s = q0 * lo.x + q1 * lo.y + q2 * hi.x + q3 * hi.y;
    ((float*)&o)[j] = __logf(s);
  }
  *(float4*)&out[(size_t)t * V_ + v] = o;
}

extern "C" void kernel_launch(void* const* d_in, const int* in_sizes, int n_in,
                              void* d_out, int out_size, void* d_ws, size_t ws_size,
                              hipStream_t stream) {
  const float* hs       = (const float*)d_in[0];
  const float* W_prior  = (const float*)d_in[1];
  const float* b_prior  = (const float*)d_in[2];
  const float* W_latent = (const float*)d_in[3];
  const float* b_latent = (const float*)d_in[4];
  const float* W_dec    = (const float*)d_in[5];
  const float* b_dec    = (const float*)d_in[6];
  float* out = (float*)d_out;

  char* ws = (char*)d_ws;
  __hip_bfloat16* hs_bf   = (__hip_bfloat16*)(ws);                    // 1 MB
  __hip_bfloat16* WlatT   = (__hip_bfloat16*)(ws + (1u << 20));       // 2 MB
  unsigned char*  latent8 = (unsigned char*)(ws + 3u * (1u << 20));   // 2 MB [4096][512]
  unsigned char*  WdecT8  = (unsigned char*)(ws + 5u * (1u << 20));   // 16.4 MB [32000][512]
  float* log_coef = (float*)(ws + 22u * (1u << 20));                  // 16 KB
  float* S = log_coef + AROWS;                                        // 16 KB
  float* q = S + AROWS;                                               // 16 KB
  unsigned int* pbuf = (unsigned int*)(ws + 23u * (1u << 20));        // 131 MB

  const size_t needA = 23u * (1u << 20) + (size_t)L_ * V_ * 4;
  const bool pathA = ws_size >= needA;

  prep_kernel<<<PREP_TOT, 256, 0, stream>>>(hs, W_prior, b_prior, W_latent, W_dec,
                                            hs_bf, WlatT, WdecT8, log_coef, S);
  latent_gemm<<<dim3((E_ * D_) / 128, L_ / 128), 256, 0, stream>>>(hs_bf, WlatT, b_latent, latent8);

  if (pathA) {
    mos_gemm<3><<<8 * 16 * 63, 256, 0, stream>>>(latent8, WdecT8, b_dec, nullptr, S, nullptr, pbuf);
    combine_kernel<<<dim3(32, L_), 256, 0, stream>>>(pbuf, log_coef, S, out);
  } else {
    mos_gemm<1><<<8 * 16 * 63, 256, 0, stream>>>(latent8, WdecT8, b_dec, nullptr, S, nullptr, nullptr);
    qk_kernel<<<(AROWS + 255) / 256, 256, 0, stream>>>(log_coef, S, q);
    mos_gemm<2><<<8 * 16 * 63, 256, 0, stream>>>(latent8, WdecT8, b_dec, q, nullptr, out, nullptr);
  }
}

// Round 6
// 380.621 us; speedup vs baseline: 1.0592x; 1.0592x over previous
//
#include <hip/hip_runtime.h>
#include <hip/hip_bf16.h>
#include <hip/hip_fp16.h>
#include <math.h>

// MOSDecoder round 12:
//  - Ledger: total = mos_gemm + ~221us CONSTANT across r6-r11 -> the other
//    kernels (prep 9808 tiny blocks, latent_gemm 128 blocks on 256 CUs,
//    combine 32768 4KB-blocks) are the bigger target. This round:
//      * combine: 2048 blocks, per-row grid-stride, q hoisted -> BW-bound.
//      * latent_gemm: 128x64 tile -> 256 blocks (full machine).
//      * prep: 64x64 transpose tiles (4000 blocks W_dec, 256 W_latent,
//        256 hs-cvt) -> PREP_TOT 4784.
//  - mos_gemm: exact r6 body (best, 127.8us) + DPP row16 epilogue reduce
//    (replaces __shfl_xor: the 1024 conflict-cyc/block in r6/r8/r10 was the
//    epilogue bpermutes, not frag reads) + launch_bounds(256,3).
//  - r11 lesson: region LDS layout fixed conflicts but un-coalesced the
//    global staging (16 rows @512B stride per 16-lane group) -> reverted.

#define D_ 512
#define E_ 4
#define V_ 32000
#define L_ 1024
#define AROWS (L_ * E_)   // 4096

#define SA_ 0x7D7D7D7D    // e8m0 2^-2 (latent stored x4)
#define SB_ 0x7B7B7B7B    // e8m0 2^-4 (W_dec stored x16)

typedef __attribute__((ext_vector_type(8))) short s16x8;
typedef __attribute__((ext_vector_type(4))) float f32x4;
typedef __attribute__((ext_vector_type(2))) float f32x2;
typedef __attribute__((ext_vector_type(4))) int i32x4;
typedef __attribute__((ext_vector_type(8))) int i32x8;
typedef __attribute__((ext_vector_type(4))) unsigned int u32x4;
typedef const __attribute__((address_space(1))) char* gp1_t;
typedef __attribute__((address_space(3))) char* lp3_t;

__device__ __forceinline__ void gload_lds16(const void* g, void* l) {
  __builtin_amdgcn_global_load_lds((gp1_t)g, (lp3_t)l, 16, 0, 0);
}

// sum across each 16-lane row via DPP (VALU pipe, no LDS). Result in lane 15.
__device__ __forceinline__ float dpp_row16_sum(float x) {
  int t;
  t = __builtin_amdgcn_update_dpp(0, __float_as_int(x), 0x111, 0xF, 0xF, true);
  x += __int_as_float(t);
  t = __builtin_amdgcn_update_dpp(0, __float_as_int(x), 0x112, 0xF, 0xF, true);
  x += __int_as_float(t);
  t = __builtin_amdgcn_update_dpp(0, __float_as_int(x), 0x114, 0xF, 0xF, true);
  x += __int_as_float(t);
  t = __builtin_amdgcn_update_dpp(0, __float_as_int(x), 0x118, 0xF, 0xF, true);
  x += __int_as_float(t);
  return x;
}

// ================= fused prep =================
// [0,4000)      tcvt W_dec [512][32000] -> fp8 WdecT8 [32000][512] (x16), 64x64 tiles
// [4000,4256)   tcvt W_latent -> bf16 WlatT [2048][512], 64x64 tiles
// [4256,4512)   cvt hs -> bf16 (8 elems/thread)
// [4512,4768)   prior log-softmax
// [4768,4784)   zero S
#define PREP_DEC  4000
#define PREP_LAT  (PREP_DEC + 256)
#define PREP_CVT  (PREP_LAT + 256)
#define PREP_PRI  (PREP_CVT + 256)
#define PREP_TOT  (PREP_PRI + 16)

__global__ __launch_bounds__(256) void prep_kernel(
    const float* __restrict__ hs, const float* __restrict__ W_prior,
    const float* __restrict__ b_prior, const float* __restrict__ W_latent,
    const float* __restrict__ W_dec,
    __hip_bfloat16* __restrict__ hs_bf, __hip_bfloat16* __restrict__ WlatT,
    unsigned char* __restrict__ WdecT8, float* __restrict__ log_coef,
    float* __restrict__ S) {
  __shared__ float tileS[64 * 65];   // 64x64 tile, pad 65 (odd) for transpose reads
  const int b = blockIdx.x;
  const int tid = threadIdx.x;

  if (b < PREP_DEC) {
    // W_dec [512][32000] -> WdecT8 [32000][512]; tile 64 d-rows x 64 v-cols.
    const int vb = (b % 500) * 64;
    const int db = (b / 500) * 64;
    {
      const int r = tid >> 2, c0 = (tid & 3) * 16;
      const float* src = W_dec + (size_t)(db + r) * V_ + vb + c0;
      float* t = &tileS[r * 65 + c0];
      #pragma unroll
      for (int j = 0; j < 4; ++j) {
        float4 a = *(const float4*)(src + j * 4);
        t[j * 4 + 0] = a.x; t[j * 4 + 1] = a.y; t[j * 4 + 2] = a.z; t[j * 4 + 3] = a.w;
      }
    }
    __syncthreads();
    {
      const int vr = tid >> 2, d0 = (tid & 3) * 16;
      float t16[16];
      #pragma unroll
      for (int j = 0; j < 16; ++j) t16[j] = tileS[(d0 + j) * 65 + vr] * 16.f;
      unsigned int u[4];
      #pragma unroll
      for (int j = 0; j < 4; ++j) {
        unsigned int w = 0;
        w = __builtin_amdgcn_cvt_pk_fp8_f32(t16[j * 4 + 0], t16[j * 4 + 1], w, false);
        w = __builtin_amdgcn_cvt_pk_fp8_f32(t16[j * 4 + 2], t16[j * 4 + 3], w, true);
        u[j] = w;
      }
      u32x4 uu = {u[0], u[1], u[2], u[3]};
      *(u32x4*)&WdecT8[(size_t)(vb + vr) * D_ + db + d0] = uu;
    }
  } else if (b < PREP_LAT) {
    // W_latent [512][2048] -> WlatT [2048][512] bf16; 64x64 tiles.
    const int bb = b - PREP_DEC;
    const int cb = (bb & 31) * 64, rb = (bb >> 5) * 64;
    const int C = E_ * D_;
    {
      const int r = tid >> 2, c0 = (tid & 3) * 16;
      const float* src = W_latent + (size_t)(rb + r) * C + cb + c0;
      float* t = &tileS[r * 65 + c0];
      #pragma unroll
      for (int j = 0; j < 4; ++j) {
        float4 a = *(const float4*)(src + j * 4);
        t[j * 4 + 0] = a.x; t[j * 4 + 1] = a.y; t[j * 4 + 2] = a.z; t[j * 4 + 3] = a.w;
      }
    }
    __syncthreads();
    {
      const int cr = tid >> 2, r0 = (tid & 3) * 16;
      __hip_bfloat16 tmp[16];
      #pragma unroll
      for (int j = 0; j < 16; ++j) tmp[j] = __float2bfloat16(tileS[(r0 + j) * 65 + cr]);
      __hip_bfloat16* dst = &WlatT[(size_t)(cb + cr) * D_ + rb + r0];
      *(uint4*)dst = *(uint4*)&tmp[0];
      *(uint4*)(dst + 8) = *(uint4*)&tmp[8];
    }
  } else if (b < PREP_CVT) {
    int i = ((b - PREP_LAT) * 256 + tid) * 8;
    float4 v0 = *(const float4*)(hs + i);
    float4 v1 = *(const float4*)(hs + i + 4);
    __hip_bfloat16 tmp[8];
    tmp[0] = __float2bfloat16(v0.x); tmp[1] = __float2bfloat16(v0.y);
    tmp[2] = __float2bfloat16(v0.z); tmp[3] = __float2bfloat16(v0.w);
    tmp[4] = __float2bfloat16(v1.x); tmp[5] = __float2bfloat16(v1.y);
    tmp[6] = __float2bfloat16(v1.z); tmp[7] = __float2bfloat16(v1.w);
    *(uint4*)&hs_bf[i] = *(uint4*)&tmp[0];
  } else if (b < PREP_PRI) {
    int t = (b - PREP_CVT) * 4 + (tid >> 6);
    int lane = tid & 63;
    float a0 = 0.f, a1 = 0.f, a2 = 0.f, a3 = 0.f;
    for (int d = lane; d < D_; d += 64) {
      float h = hs[t * D_ + d];
      float4 w = ((const float4*)W_prior)[d];
      a0 += h * w.x; a1 += h * w.y; a2 += h * w.z; a3 += h * w.w;
    }
    #pragma unroll
    for (int off = 32; off > 0; off >>= 1) {
      a0 += __shfl_xor(a0, off);
      a1 += __shfl_xor(a1, off);
      a2 += __shfl_xor(a2, off);
      a3 += __shfl_xor(a3, off);
    }
    a0 += b_prior[0]; a1 += b_prior[1]; a2 += b_prior[2]; a3 += b_prior[3];
    float mx = fmaxf(fmaxf(a0, a1), fmaxf(a2, a3));
    float ls = mx + logf(expf(a0 - mx) + expf(a1 - mx) + expf(a2 - mx) + expf(a3 - mx));
    if (lane == 0) {
      log_coef[t * 4 + 0] = a0 - ls;
      log_coef[t * 4 + 1] = a1 - ls;
      log_coef[t * 4 + 2] = a2 - ls;
      log_coef[t * 4 + 3] = a3 - ls;
    }
  } else {
    S[(b - PREP_PRI) * 256 + tid] = 0.f;
  }
}

// ---- q = exp(log_coef)/S (fallback path only) ----
__global__ void qk_kernel(const float* __restrict__ log_coef, const float* __restrict__ S,
                          float* __restrict__ q) {
  int i = blockIdx.x * blockDim.x + threadIdx.x;
  if (i < AROWS) q[i] = __expf(log_coef[i]) / S[i];
}

// ---- latent = fp8(4*tanh(hs @ W_latent + b)) -> [L][E*D] == [4096][512]
//      tile 128x64 -> grid (32,8) = 256 blocks (full machine). ----
__global__ __launch_bounds__(256, 2) void latent_gemm(
    const __hip_bfloat16* __restrict__ Abf, const __hip_bfloat16* __restrict__ BT,
    const float* __restrict__ b_latent, unsigned char* __restrict__ latent8) {
  __shared__ short As[128 * 32];
  __shared__ short Bs[64 * 32];
  const int tid = threadIdx.x;
  const int wave = tid >> 6, lane = tid & 63;
  const int wm = wave >> 1, wn = wave & 1;
  const int m0 = blockIdx.y * 128;
  const int n0 = blockIdx.x * 64;
  const int lrow = lane & 15;
  const int kgrp = lane >> 4;
  const int srow = wave * 16 + (lane >> 2);
  const int scol = (lane & 3) * 8;

  f32x4 acc[4][2];
  #pragma unroll
  for (int mt = 0; mt < 4; ++mt)
    #pragma unroll
    for (int nt = 0; nt < 2; ++nt) acc[mt][nt] = f32x4{0.f, 0.f, 0.f, 0.f};

  for (int kt = 0; kt < 16; ++kt) {
    const int k0 = kt * 32;
    #pragma unroll
    for (int j = 0; j < 2; ++j) {
      const int row = j * 64 + srow;
      gload_lds16(Abf + (size_t)(m0 + row) * D_ + k0 + scol, &As[(j * 256 + wave * 64) * 8]);
    }
    gload_lds16(BT + (size_t)(n0 + srow) * D_ + k0 + scol, &Bs[(wave * 64) * 8]);
    __syncthreads();
    s16x8 af[4], bfr[2];
    #pragma unroll
    for (int mt = 0; mt < 4; ++mt) af[mt] = *(const s16x8*)&As[(wm * 64 + mt * 16 + lrow) * 32 + kgrp * 8];
    #pragma unroll
    for (int nt = 0; nt < 2; ++nt) bfr[nt] = *(const s16x8*)&Bs[(wn * 32 + nt * 16 + lrow) * 32 + kgrp * 8];
    #pragma unroll
    for (int mt = 0; mt < 4; ++mt)
      #pragma unroll
      for (int nt = 0; nt < 2; ++nt)
        acc[mt][nt] = __builtin_amdgcn_mfma_f32_16x16x32_bf16(af[mt], bfr[nt], acc[mt][nt], 0, 0, 0);
    __syncthreads();
  }

  float blat[2];
  #pragma unroll
  for (int nt = 0; nt < 2; ++nt) blat[nt] = b_latent[n0 + wn * 32 + nt * 16 + lrow];
  #pragma unroll
  for (int mt = 0; mt < 4; ++mt)
    #pragma unroll
    for (int r = 0; r < 4; ++r) {
      const int row = m0 + wm * 64 + mt * 16 + kgrp * 4 + r;  // token*4+e
      #pragma unroll
      for (int nt = 0; nt < 2; ++nt) {
        const int col = n0 + wn * 32 + nt * 16 + lrow;
        float v = tanhf(acc[mt][nt][r] + blat[nt]) * 4.f;     // x4: e4m3 + HW scale 2^-2
        int u = __builtin_amdgcn_cvt_pk_fp8_f32(v, v, 0, false);
        latent8[(size_t)row * (E_ * D_) + col] = (unsigned char)(u & 0xff);
      }
    }
}

// ---- decoder GEMM (MX-fp8, K=128): exact r6 body + DPP epilogue reduce.
//      MODE 1: S only. MODE 2: out directly. MODE 3: S + p packed fp8. ----
template <int MODE>
__global__ __launch_bounds__(256, 3) void mos_gemm(
    const unsigned char* __restrict__ A8,      // [4096][512] fp8 (x4), row = l*4+e
    const unsigned char* __restrict__ W8,      // [32000][512] fp8 (x16)
    const float* __restrict__ b_dec,
    const float* __restrict__ q,               // [4096] (MODE 2)
    float* __restrict__ S,                     // [4096] (MODE 1/3)
    float* __restrict__ out,                   // [1024][32000] (MODE 2)
    unsigned int* __restrict__ pbuf) {         // [1024][32000] (MODE 3)
  const int bid = blockIdx.x;
  const int xcd = bid & 7;
  const int idx = bid >> 3;
  const int mg = xcd >> 2;
  const int vg = xcd & 3;
  const int vt = vg * 63 + (idx >> 4);
  const int mtile = mg * 16 + (idx & 15);
  if (vt >= V_ / 128) return;
  const int m0 = mtile * 128;
  const int v0 = vt * 128;

  __shared__ __attribute__((aligned(16))) unsigned char As[128 * 128];
  __shared__ __attribute__((aligned(16))) unsigned char Bs[128 * 128];
  const int tid = threadIdx.x;
  const int wave = tid >> 6, lane = tid & 63;
  const int wm = wave >> 1, wn = wave & 1;
  const int lrow = lane & 15;
  const int kgrp = lane >> 4;
  const int srow8 = wave * 8 + (lane >> 3);      // staging row within 32-row group
  const int schunk = lane & 7;                   // 16-B chunk within 128-B row

  float bdec[4];
  #pragma unroll
  for (int nt = 0; nt < 4; ++nt) bdec[nt] = b_dec[v0 + wn * 64 + nt * 16 + lrow];

  f32x4 acc[4][4];
  #pragma unroll
  for (int mt = 0; mt < 4; ++mt)
    #pragma unroll
    for (int nt = 0; nt < 4; ++nt) acc[mt][nt] = f32x4{0.f, 0.f, 0.f, 0.f};

  for (int kt = 0; kt < 4; ++kt) {
    const int kb = kt * 128;
    #pragma unroll
    for (int j = 0; j < 4; ++j) {
      const int row = j * 32 + srow8;
      const int sc = (schunk ^ (row & 7)) * 16;  // XOR chunk swizzle
      gload_lds16(A8 + (size_t)(m0 + row) * D_ + kb + sc, &As[(j * 32 + wave * 8) * 128]);
      gload_lds16(W8 + (size_t)(v0 + row) * D_ + kb + sc, &Bs[(j * 32 + wave * 8) * 128]);
    }
    __syncthreads();
    i32x8 af[4], bfr[4];
    #pragma unroll
    for (int mt = 0; mt < 4; ++mt) {
      const int row = wm * 64 + mt * 16 + lrow;
      const int s = lrow & 7;
      i32x4 lo = *(const i32x4*)&As[row * 128 + (((kgrp * 2) ^ s) * 16)];
      i32x4 hi = *(const i32x4*)&As[row * 128 + (((kgrp * 2 + 1) ^ s) * 16)];
      af[mt] = __builtin_shufflevector(lo, hi, 0, 1, 2, 3, 4, 5, 6, 7);
    }
    #pragma unroll
    for (int nt = 0; nt < 4; ++nt) {
      const int row = wn * 64 + nt * 16 + lrow;
      const int s = lrow & 7;
      i32x4 lo = *(const i32x4*)&Bs[row * 128 + (((kgrp * 2) ^ s) * 16)];
      i32x4 hi = *(const i32x4*)&Bs[row * 128 + (((kgrp * 2 + 1) ^ s) * 16)];
      bfr[nt] = __builtin_shufflevector(lo, hi, 0, 1, 2, 3, 4, 5, 6, 7);
    }
    #pragma unroll
    for (int mt = 0; mt < 4; ++mt)
      #pragma unroll
      for (int nt = 0; nt < 4; ++nt)
        acc[mt][nt] = __builtin_amdgcn_mfma_scale_f32_16x16x128_f8f6f4(
            af[mt], bfr[nt], acc[mt][nt], 0, 0, 0, SA_, 0, SB_);
    __syncthreads();
  }

  if constexpr (MODE == 1 || MODE == 3) {
    #pragma unroll
    for (int mt = 0; mt < 4; ++mt) {
      const int row4 = m0 + wm * 64 + mt * 16 + kgrp * 4;
      const int token = row4 >> 2;
      float p0 = 0.f, p1 = 0.f, p2 = 0.f, p3 = 0.f;
      #pragma unroll
      for (int nt = 0; nt < 4; ++nt) {
        float e0 = __expf(acc[mt][nt][0] + bdec[nt]);
        float e1 = __expf(acc[mt][nt][1] + bdec[nt]);
        float e2 = __expf(acc[mt][nt][2] + bdec[nt]);
        float e3 = __expf(acc[mt][nt][3] + bdec[nt]);
        p0 += e0; p1 += e1; p2 += e2; p3 += e3;
        if constexpr (MODE == 3) {
          const int v = v0 + wn * 64 + nt * 16 + lrow;
          int u = 0;
          u = __builtin_amdgcn_cvt_pk_fp8_f32(e0, e1, u, false);
          u = __builtin_amdgcn_cvt_pk_fp8_f32(e2, e3, u, true);
          __builtin_nontemporal_store((unsigned int)u, &pbuf[(size_t)token * V_ + v]);
        }
      }
      // DPP row16 reduce on the VALU pipe (was __shfl_xor -> LDS bpermutes).
      p0 = dpp_row16_sum(p0);
      p1 = dpp_row16_sum(p1);
      p2 = dpp_row16_sum(p2);
      p3 = dpp_row16_sum(p3);
      if (lrow == 15) {
        atomicAdd(&S[row4 + 0], p0);
        atomicAdd(&S[row4 + 1], p1);
        atomicAdd(&S[row4 + 2], p2);
        atomicAdd(&S[row4 + 3], p3);
      }
    }
  } else {  // MODE == 2
    #pragma unroll
    for (int mt = 0; mt < 4; ++mt) {
      const int row4 = m0 + wm * 64 + mt * 16 + kgrp * 4;
      const float4 qv = *(const float4*)&q[row4];
      const int token = row4 >> 2;
      #pragma unroll
      for (int nt = 0; nt < 4; ++nt) {
        float v = qv.x * __expf(acc[mt][nt][0] + bdec[nt]) +
                  qv.y * __expf(acc[mt][nt][1] + bdec[nt]) +
                  qv.z * __expf(acc[mt][nt][2] + bdec[nt]) +
                  qv.w * __expf(acc[mt][nt][3] + bdec[nt]);
        out[(size_t)token * V_ + v0 + wn * 64 + nt * 16 + lrow] = __logf(v);
      }
    }
  }
}

// ---- combine: out[t][v] = log(sum_e q_e * p8[t][v][e])
//      grid (2, L_): per-row halves, q hoisted, coalesced grid-stride. ----
__global__ __launch_bounds__(256) void combine_kernel(
    const unsigned int* __restrict__ pbuf,
    const float* __restrict__ lc, const float* __restrict__ S,
    float* __restrict__ out) {
  const int t = blockIdx.y;
  const int vbase = blockIdx.x * (V_ / 2);
  const int vend = vbase + (V_ / 2);
  const float4 lcv = ((const float4*)lc)[t];
  const float4 Sv = ((const float4*)S)[t];
  const float q0 = __expf(lcv.x) / Sv.x;
  const float q1 = __expf(lcv.y) / Sv.y;
  const float q2 = __expf(lcv.z) / Sv.z;
  const float q3 = __expf(lcv.w) / Sv.w;
  const unsigned int* prow = pbuf + (size_t)t * V_;
  float* orow = out + (size_t)t * V_;
  for (int v = vbase + threadIdx.x * 4; v < vend; v += 1024) {
    u32x4 u = __builtin_nontemporal_load((const u32x4*)(prow + v));
    float4 o;
    #pragma unroll
    for (int j = 0; j < 4; ++j) {
      unsigned int w = u[j];
      f32x2 lo = __builtin_amdgcn_cvt_pk_f32_fp8(w, false);
      f32x2 hi = __builtin_amdgcn_cvt_pk_f32_fp8(w, true);
      float s = q0 * lo.x + q1 * lo.y + q2 * hi.x + q3 * hi.y;
      ((float*)&o)[j] = __logf(s);
    }
    *(float4*)(orow + v) = o;
  }
}

extern "C" void kernel_launch(void* const* d_in, const int* in_sizes, int n_in,
                              void* d_out, int out_size, void* d_ws, size_t ws_size,
                              hipStream_t stream) {
  const float* hs       = (const float*)d_in[0];
  const float* W_prior  = (const float*)d_in[1];
  const float* b_prior  = (const float*)d_in[2];
  const float* W_latent = (const float*)d_in[3];
  const float* b_latent = (const float*)d_in[4];
  const float* W_dec    = (const float*)d_in[5];
  const float* b_dec    = (const float*)d_in[6];
  float* out = (float*)d_out;

  char* ws = (char*)d_ws;
  __hip_bfloat16* hs_bf   = (__hip_bfloat16*)(ws);                    // 1 MB
  __hip_bfloat16* WlatT   = (__hip_bfloat16*)(ws + (1u << 20));       // 2 MB
  unsigned char*  latent8 = (unsigned char*)(ws + 3u * (1u << 20));   // 2 MB [4096][512]
  unsigned char*  WdecT8  = (unsigned char*)(ws + 5u * (1u << 20));   // 16.4 MB [32000][512]
  float* log_coef = (float*)(ws + 22u * (1u << 20));                  // 16 KB
  float* S = log_coef + AROWS;                                        // 16 KB
  float* q = S + AROWS;                                               // 16 KB
  unsigned int* pbuf = (unsigned int*)(ws + 23u * (1u << 20));        // 131 MB

  const size_t needA = 23u * (1u << 20) + (size_t)L_ * V_ * 4;
  const bool pathA = ws_size >= needA;

  prep_kernel<<<PREP_TOT, 256, 0, stream>>>(hs, W_prior, b_prior, W_latent, W_dec,
                                            hs_bf, WlatT, WdecT8, log_coef, S);
  latent_gemm<<<dim3((E_ * D_) / 64, L_ / 128), 256, 0, stream>>>(hs_bf, WlatT, b_latent, latent8);

  if (pathA) {
    mos_gemm<3><<<8 * 16 * 63, 256, 0, stream>>>(latent8, WdecT8, b_dec, nullptr, S, nullptr, pbuf);
    combine_kernel<<<dim3(2, L_), 256, 0, stream>>>(pbuf, log_coef, S, out);
  } else {
    mos_gemm<1><<<8 * 16 * 63, 256, 0, stream>>>(latent8, WdecT8, b_dec, nullptr, S, nullptr, nullptr);
    qk_kernel<<<(AROWS + 255) / 256, 256, 0, stream>>>(log_coef, S, q);
    mos_gemm<2><<<8 * 16 * 63, 256, 0, stream>>>(latent8, WdecT8, b_dec, q, nullptr, out, nullptr);
  }
}

// Round 7
// 358.122 us; speedup vs baseline: 1.1257x; 1.0628x over previous
//
#include <hip/hip_runtime.h>
#include <hip/hip_bf16.h>
#include <hip/hip_fp16.h>
#include <math.h>

// MOSDecoder round 13:
//  - Base = round-6 kernel (best mos_gemm 127.8us, total 351.3) with TWO
//    surgical changes:
//    (1) mos_gemm MODE3: pbuf stores LDS-staged. p-tile = 32tok x 128v x 4B
//        = 16KB, reuses dead As after K-loop; epilogue writes u32s to LDS
//        (+8*token swizzle -> 2-way max), barrier, then u32x4 nt stores =
//        full 128B-line streams. Fixes the measured write amplification
//        (4B nt scatter: 172MB @2blk/CU -> 343 @3 -> 757 @r7; ideal 131MB).
//        S-reduce via DPP row16 (validated r12, VALU pipe).
//    (2) combine: grid (8,L) grid-stride (q computed once/block, nt loads
//        pipelined) instead of 32768 one-shot blocks.
//  - r12 reverted: prep 64x33-tile 9808 blocks, latent 128x128 grid(16,8).
//  - Known open item: fragment ds_reads are the 8.192M conflict source
//    (bank = 4*chunk, row term vanishes at 128B stride) -- structural,
//    ~10%/block, future round.

#define D_ 512
#define E_ 4
#define V_ 32000
#define L_ 1024
#define AROWS (L_ * E_)   // 4096

#define SA_ 0x7D7D7D7D    // e8m0 2^-2 (latent stored x4)
#define SB_ 0x7B7B7B7B    // e8m0 2^-4 (W_dec stored x16)

typedef __attribute__((ext_vector_type(8))) short s16x8;
typedef __attribute__((ext_vector_type(4))) float f32x4;
typedef __attribute__((ext_vector_type(2))) float f32x2;
typedef __attribute__((ext_vector_type(4))) int i32x4;
typedef __attribute__((ext_vector_type(8))) int i32x8;
typedef __attribute__((ext_vector_type(4))) unsigned int u32x4;
typedef const __attribute__((address_space(1))) char* gp1_t;
typedef __attribute__((address_space(3))) char* lp3_t;

__device__ __forceinline__ void gload_lds16(const void* g, void* l) {
  __builtin_amdgcn_global_load_lds((gp1_t)g, (lp3_t)l, 16, 0, 0);
}

// sum across each 16-lane row via DPP (VALU pipe, no LDS). Result in lane 15.
__device__ __forceinline__ float dpp_row16_sum(float x) {
  int t;
  t = __builtin_amdgcn_update_dpp(0, __float_as_int(x), 0x111, 0xF, 0xF, true);
  x += __int_as_float(t);
  t = __builtin_amdgcn_update_dpp(0, __float_as_int(x), 0x112, 0xF, 0xF, true);
  x += __int_as_float(t);
  t = __builtin_amdgcn_update_dpp(0, __float_as_int(x), 0x114, 0xF, 0xF, true);
  x += __int_as_float(t);
  t = __builtin_amdgcn_update_dpp(0, __float_as_int(x), 0x118, 0xF, 0xF, true);
  x += __int_as_float(t);
  return x;
}

// ================= fused prep =================
// [0,8000)      tcvt W_dec [512][32000] -> fp8 WdecT8 [32000][512] (x16)
// [8000,9024)   tcvt W_latent -> bf16 WlatT [2048][512]
// [9024,9536)   cvt hs -> bf16
// [9536,9792)   prior log-softmax
// [9792,9808)   zero S
#define PREP_DEC  8000
#define PREP_LAT  (PREP_DEC + 1024)
#define PREP_CVT  (PREP_LAT + 512)
#define PREP_PRI  (PREP_CVT + 256)
#define PREP_TOT  (PREP_PRI + 16)

__global__ __launch_bounds__(256) void prep_kernel(
    const float* __restrict__ hs, const float* __restrict__ W_prior,
    const float* __restrict__ b_prior, const float* __restrict__ W_latent,
    const float* __restrict__ W_dec,
    __hip_bfloat16* __restrict__ hs_bf, __hip_bfloat16* __restrict__ WlatT,
    unsigned char* __restrict__ WdecT8, float* __restrict__ log_coef,
    float* __restrict__ S) {
  __shared__ float tileS[64 * 33];
  const int b = blockIdx.x;
  const int tid = threadIdx.x;

  if (b < PREP_DEC) {
    // W_dec [512][32000] -> WdecT8 [32000][512]; tile 64 d-rows x 32 v-cols.
    const int vb = (b % 1000) * 32;
    const int db = (b / 1000) * 64;
    {
      const int r = tid >> 2, c0 = (tid & 3) * 8;
      const float* src = W_dec + (size_t)(db + r) * V_ + vb + c0;
      float4 a0 = *(const float4*)src;
      float4 a1 = *(const float4*)(src + 4);
      float* t = &tileS[r * 33 + c0];
      t[0] = a0.x; t[1] = a0.y; t[2] = a0.z; t[3] = a0.w;
      t[4] = a1.x; t[5] = a1.y; t[6] = a1.z; t[7] = a1.w;
    }
    __syncthreads();
    {
      const int vr = tid >> 3, d0 = (tid & 7) * 8;
      float t8[8];
      #pragma unroll
      for (int j = 0; j < 8; ++j) t8[j] = tileS[(d0 + j) * 33 + vr] * 16.f;
      unsigned int u0 = 0, u1 = 0;
      u0 = __builtin_amdgcn_cvt_pk_fp8_f32(t8[0], t8[1], u0, false);
      u0 = __builtin_amdgcn_cvt_pk_fp8_f32(t8[2], t8[3], u0, true);
      u1 = __builtin_amdgcn_cvt_pk_fp8_f32(t8[4], t8[5], u1, false);
      u1 = __builtin_amdgcn_cvt_pk_fp8_f32(t8[6], t8[7], u1, true);
      uint2 uu = {u0, u1};
      *(uint2*)&WdecT8[(size_t)(vb + vr) * D_ + db + d0] = uu;
    }
  } else if (b < PREP_LAT) {
    const int bb = b - PREP_DEC;
    const int cb = (bb & 63) * 32, rb = (bb >> 6) * 32;
    const int C = E_ * D_, R = D_;
    const int tx = tid & 31, ty = tid >> 5;  // 32x8
    #pragma unroll
    for (int j = 0; j < 32; j += 8)
      tileS[(ty + j) * 33 + tx] = W_latent[(size_t)(rb + ty + j) * C + cb + tx];
    __syncthreads();
    #pragma unroll
    for (int j = 0; j < 32; j += 8)
      WlatT[(size_t)(cb + ty + j) * R + rb + tx] = __float2bfloat16(tileS[tx * 33 + ty + j]);
  } else if (b < PREP_CVT) {
    int i = ((b - PREP_LAT) * 256 + tid) * 4;
    float4 v = *(const float4*)(hs + i);
    hs_bf[i + 0] = __float2bfloat16(v.x);
    hs_bf[i + 1] = __float2bfloat16(v.y);
    hs_bf[i + 2] = __float2bfloat16(v.z);
    hs_bf[i + 3] = __float2bfloat16(v.w);
  } else if (b < PREP_PRI) {
    int t = (b - PREP_CVT) * 4 + (tid >> 6);
    int lane = tid & 63;
    float a0 = 0.f, a1 = 0.f, a2 = 0.f, a3 = 0.f;
    for (int d = lane; d < D_; d += 64) {
      float h = hs[t * D_ + d];
      float4 w = ((const float4*)W_prior)[d];
      a0 += h * w.x; a1 += h * w.y; a2 += h * w.z; a3 += h * w.w;
    }
    #pragma unroll
    for (int off = 32; off > 0; off >>= 1) {
      a0 += __shfl_xor(a0, off);
      a1 += __shfl_xor(a1, off);
      a2 += __shfl_xor(a2, off);
      a3 += __shfl_xor(a3, off);
    }
    a0 += b_prior[0]; a1 += b_prior[1]; a2 += b_prior[2]; a3 += b_prior[3];
    float mx = fmaxf(fmaxf(a0, a1), fmaxf(a2, a3));
    float ls = mx + logf(expf(a0 - mx) + expf(a1 - mx) + expf(a2 - mx) + expf(a3 - mx));
    if (lane == 0) {
      log_coef[t * 4 + 0] = a0 - ls;
      log_coef[t * 4 + 1] = a1 - ls;
      log_coef[t * 4 + 2] = a2 - ls;
      log_coef[t * 4 + 3] = a3 - ls;
    }
  } else {
    S[(b - PREP_PRI) * 256 + tid] = 0.f;
  }
}

// ---- q = exp(log_coef)/S (fallback path only) ----
__global__ void qk_kernel(const float* __restrict__ log_coef, const float* __restrict__ S,
                          float* __restrict__ q) {
  int i = blockIdx.x * blockDim.x + threadIdx.x;
  if (i < AROWS) q[i] = __expf(log_coef[i]) / S[i];
}

// ---- latent = fp8(4*tanh(hs @ W_latent + b)) -> [L][E*D] == [4096][512] ----
__global__ __launch_bounds__(256, 2) void latent_gemm(
    const __hip_bfloat16* __restrict__ Abf, const __hip_bfloat16* __restrict__ BT,
    const float* __restrict__ b_latent, unsigned char* __restrict__ latent8) {
  __shared__ short As[128 * 32];
  __shared__ short Bs[128 * 32];
  const int tid = threadIdx.x;
  const int wave = tid >> 6, lane = tid & 63;
  const int wm = wave >> 1, wn = wave & 1;
  const int m0 = blockIdx.y * 128;
  const int n0 = blockIdx.x * 128;
  const int lrow = lane & 15;
  const int kgrp = lane >> 4;
  const int srow = wave * 16 + (lane >> 2);
  const int scol = (lane & 3) * 8;

  f32x4 acc[4][4];
  #pragma unroll
  for (int mt = 0; mt < 4; ++mt)
    #pragma unroll
    for (int nt = 0; nt < 4; ++nt) acc[mt][nt] = f32x4{0.f, 0.f, 0.f, 0.f};

  for (int kt = 0; kt < 16; ++kt) {
    const int k0 = kt * 32;
    #pragma unroll
    for (int j = 0; j < 2; ++j) {
      const int row = j * 64 + srow;
      gload_lds16(Abf + (size_t)(m0 + row) * D_ + k0 + scol, &As[(j * 256 + wave * 64) * 8]);
      gload_lds16(BT + (size_t)(n0 + row) * D_ + k0 + scol, &Bs[(j * 256 + wave * 64) * 8]);
    }
    __syncthreads();
    s16x8 af[4], bfr[4];
    #pragma unroll
    for (int mt = 0; mt < 4; ++mt) af[mt] = *(const s16x8*)&As[(wm * 64 + mt * 16 + lrow) * 32 + kgrp * 8];
    #pragma unroll
    for (int nt = 0; nt < 4; ++nt) bfr[nt] = *(const s16x8*)&Bs[(wn * 64 + nt * 16 + lrow) * 32 + kgrp * 8];
    #pragma unroll
    for (int mt = 0; mt < 4; ++mt)
      #pragma unroll
      for (int nt = 0; nt < 4; ++nt)
        acc[mt][nt] = __builtin_amdgcn_mfma_f32_16x16x32_bf16(af[mt], bfr[nt], acc[mt][nt], 0, 0, 0);
    __syncthreads();
  }

  float blat[4];
  #pragma unroll
  for (int nt = 0; nt < 4; ++nt) blat[nt] = b_latent[n0 + wn * 64 + nt * 16 + lrow];
  #pragma unroll
  for (int mt = 0; mt < 4; ++mt)
    #pragma unroll
    for (int r = 0; r < 4; ++r) {
      const int row = m0 + wm * 64 + mt * 16 + kgrp * 4 + r;  // token
      #pragma unroll
      for (int nt = 0; nt < 4; ++nt) {
        const int col = n0 + wn * 64 + nt * 16 + lrow;
        float v = tanhf(acc[mt][nt][r] + blat[nt]) * 4.f;     // x4: e4m3 + HW scale 2^-2
        int u = __builtin_amdgcn_cvt_pk_fp8_f32(v, v, 0, false);
        latent8[(size_t)row * (E_ * D_) + col] = (unsigned char)(u & 0xff);
      }
    }
}

// ---- decoder GEMM (MX-fp8, K=128), 128x128 tile (r6 body), LDS-staged
//      coalesced pbuf store, DPP S-reduce.
//      MODE 1: S only. MODE 2: out directly. MODE 3: S + p packed fp8. ----
template <int MODE>
__global__ __launch_bounds__(256, 2) void mos_gemm(
    const unsigned char* __restrict__ A8,      // [4096][512] fp8 (x4), row = l*4+e
    const unsigned char* __restrict__ W8,      // [32000][512] fp8 (x16)
    const float* __restrict__ b_dec,
    const float* __restrict__ q,               // [4096] (MODE 2)
    float* __restrict__ S,                     // [4096] (MODE 1/3)
    float* __restrict__ out,                   // [1024][32000] (MODE 2)
    unsigned int* __restrict__ pbuf) {         // [1024][32000] (MODE 3)
  const int bid = blockIdx.x;
  const int xcd = bid & 7;
  const int idx = bid >> 3;
  const int mg = xcd >> 2;
  const int vg = xcd & 3;
  const int vt = vg * 63 + (idx >> 4);
  const int mtile = mg * 16 + (idx & 15);
  if (vt >= V_ / 128) return;
  const int m0 = mtile * 128;
  const int v0 = vt * 128;

  __shared__ __attribute__((aligned(16))) unsigned char As[128 * 128];
  __shared__ __attribute__((aligned(16))) unsigned char Bs[128 * 128];
  const int tid = threadIdx.x;
  const int wave = tid >> 6, lane = tid & 63;
  const int wm = wave >> 1, wn = wave & 1;
  const int lrow = lane & 15;
  const int kgrp = lane >> 4;
  const int srow8 = wave * 8 + (lane >> 3);      // staging row within 32-row group
  const int schunk = lane & 7;                   // 16-B chunk within 128-B row

  float bdec[4];
  #pragma unroll
  for (int nt = 0; nt < 4; ++nt) bdec[nt] = b_dec[v0 + wn * 64 + nt * 16 + lrow];

  f32x4 acc[4][4];
  #pragma unroll
  for (int mt = 0; mt < 4; ++mt)
    #pragma unroll
    for (int nt = 0; nt < 4; ++nt) acc[mt][nt] = f32x4{0.f, 0.f, 0.f, 0.f};

  for (int kt = 0; kt < 4; ++kt) {
    const int kb = kt * 128;
    #pragma unroll
    for (int j = 0; j < 4; ++j) {
      const int row = j * 32 + srow8;
      const int sc = (schunk ^ (row & 7)) * 16;  // XOR chunk swizzle
      gload_lds16(A8 + (size_t)(m0 + row) * D_ + kb + sc, &As[(j * 32 + wave * 8) * 128]);
      gload_lds16(W8 + (size_t)(v0 + row) * D_ + kb + sc, &Bs[(j * 32 + wave * 8) * 128]);
    }
    __syncthreads();
    i32x8 af[4], bfr[4];
    #pragma unroll
    for (int mt = 0; mt < 4; ++mt) {
      const int row = wm * 64 + mt * 16 + lrow;
      const int s = lrow & 7;
      i32x4 lo = *(const i32x4*)&As[row * 128 + (((kgrp * 2) ^ s) * 16)];
      i32x4 hi = *(const i32x4*)&As[row * 128 + (((kgrp * 2 + 1) ^ s) * 16)];
      af[mt] = __builtin_shufflevector(lo, hi, 0, 1, 2, 3, 4, 5, 6, 7);
    }
    #pragma unroll
    for (int nt = 0; nt < 4; ++nt) {
      const int row = wn * 64 + nt * 16 + lrow;
      const int s = lrow & 7;
      i32x4 lo = *(const i32x4*)&Bs[row * 128 + (((kgrp * 2) ^ s) * 16)];
      i32x4 hi = *(const i32x4*)&Bs[row * 128 + (((kgrp * 2 + 1) ^ s) * 16)];
      bfr[nt] = __builtin_shufflevector(lo, hi, 0, 1, 2, 3, 4, 5, 6, 7);
    }
    #pragma unroll
    for (int mt = 0; mt < 4; ++mt)
      #pragma unroll
      for (int nt = 0; nt < 4; ++nt)
        acc[mt][nt] = __builtin_amdgcn_mfma_scale_f32_16x16x128_f8f6f4(
            af[mt], bfr[nt], acc[mt][nt], 0, 0, 0, SA_, 0, SB_);
    __syncthreads();
  }

  if constexpr (MODE == 1 || MODE == 3) {
    // p-tile staged in dead As: [32 token][128 v] u32, col swizzle +8*token
    // (bank = (v + 8t) mod 32 -> exactly 2-way for the (kgrp,lrow) lane grid).
    unsigned int* pls = (unsigned int*)As;
    #pragma unroll
    for (int mt = 0; mt < 4; ++mt) {
      const int row4 = m0 + wm * 64 + mt * 16 + kgrp * 4;
      const int tloc = wm * 16 + mt * 4 + kgrp;   // 0..31 local token
      float p0 = 0.f, p1 = 0.f, p2 = 0.f, p3 = 0.f;
      #pragma unroll
      for (int nt = 0; nt < 4; ++nt) {
        float e0 = __expf(acc[mt][nt][0] + bdec[nt]);
        float e1 = __expf(acc[mt][nt][1] + bdec[nt]);
        float e2 = __expf(acc[mt][nt][2] + bdec[nt]);
        float e3 = __expf(acc[mt][nt][3] + bdec[nt]);
        p0 += e0; p1 += e1; p2 += e2; p3 += e3;
        if constexpr (MODE == 3) {
          const int vloc = wn * 64 + nt * 16 + lrow;
          int u = 0;
          u = __builtin_amdgcn_cvt_pk_fp8_f32(e0, e1, u, false);
          u = __builtin_amdgcn_cvt_pk_fp8_f32(e2, e3, u, true);
          pls[tloc * 128 + ((vloc + 8 * tloc) & 127)] = (unsigned int)u;
        }
      }
      // DPP row16 reduce on the VALU pipe; sum lands in lane 15 of each row.
      p0 = dpp_row16_sum(p0);
      p1 = dpp_row16_sum(p1);
      p2 = dpp_row16_sum(p2);
      p3 = dpp_row16_sum(p3);
      if (lrow == 15) {
        atomicAdd(&S[row4 + 0], p0);
        atomicAdd(&S[row4 + 1], p1);
        atomicAdd(&S[row4 + 2], p2);
        atomicAdd(&S[row4 + 3], p3);
      }
    }
    if constexpr (MODE == 3) {
      __syncthreads();
      // coalesced flush: 4 x u32x4 per thread, 512B-contiguous lane runs.
      const int tokg = m0 >> 2;
      #pragma unroll
      for (int j = 0; j < 4; ++j) {
        const int slot = j * 256 + tid;        // 1024 slots of 16B
        const int tl = slot >> 5;              // token 0..31
        const int vswz = (slot & 31) * 4;      // swizzled col (mult of 4)
        const int vloc = (vswz - 8 * tl) & 127;
        u32x4 u = *(const u32x4*)&pls[tl * 128 + vswz];
        __builtin_nontemporal_store(u, (u32x4*)&pbuf[(size_t)(tokg + tl) * V_ + v0 + vloc]);
      }
    }
  } else {  // MODE == 2
    #pragma unroll
    for (int mt = 0; mt < 4; ++mt) {
      const int row4 = m0 + wm * 64 + mt * 16 + kgrp * 4;
      const float4 qv = *(const float4*)&q[row4];
      const int token = row4 >> 2;
      #pragma unroll
      for (int nt = 0; nt < 4; ++nt) {
        float v = qv.x * __expf(acc[mt][nt][0] + bdec[nt]) +
                  qv.y * __expf(acc[mt][nt][1] + bdec[nt]) +
                  qv.z * __expf(acc[mt][nt][2] + bdec[nt]) +
                  qv.w * __expf(acc[mt][nt][3] + bdec[nt]);
        out[(size_t)token * V_ + v0 + wn * 64 + nt * 16 + lrow] = __logf(v);
      }
    }
  }
}

// ---- combine: out[t][v] = log(sum_e q_e * p8[t][v][e])
//      grid (8, L_): q hoisted once per block, coalesced grid-stride. ----
__global__ __launch_bounds__(256) void combine_kernel(
    const unsigned int* __restrict__ pbuf,
    const float* __restrict__ lc, const float* __restrict__ S,
    float* __restrict__ out) {
  const int t = blockIdx.y;
  const int vbase = blockIdx.x * (V_ / 8);
  const int vend = vbase + (V_ / 8);
  const float4 lcv = ((const float4*)lc)[t];
  const float4 Sv = ((const float4*)S)[t];
  const float q0 = __expf(lcv.x) / Sv.x;
  const float q1 = __expf(lcv.y) / Sv.y;
  const float q2 = __expf(lcv.z) / Sv.z;
  const float q3 = __expf(lcv.w) / Sv.w;
  const unsigned int* prow = pbuf + (size_t)t * V_;
  float* orow = out + (size_t)t * V_;
  for (int v = vbase + threadIdx.x * 4; v < vend; v += 1024) {
    u32x4 u = __builtin_nontemporal_load((const u32x4*)(prow + v));
    float4 o;
    #pragma unroll
    for (int j = 0; j < 4; ++j) {
      unsigned int w = u[j];
      f32x2 lo = __builtin_amdgcn_cvt_pk_f32_fp8(w, false);
      f32x2 hi = __builtin_amdgcn_cvt_pk_f32_fp8(w, true);
      float s = q0 * lo.x + q1 * lo.y + q2 * hi.x + q3 * hi.y;
      ((float*)&o)[j] = __logf(s);
    }
    *(float4*)(orow + v) = o;
  }
}

extern "C" void kernel_launch(void* const* d_in, const int* in_sizes, int n_in,
                              void* d_out, int out_size, void* d_ws, size_t ws_size,
                              hipStream_t stream) {
  const float* hs       = (const float*)d_in[0];
  const float* W_prior  = (const float*)d_in[1];
  const float* b_prior  = (const float*)d_in[2];
  const float* W_latent = (const float*)d_in[3];
  const float* b_latent = (const float*)d_in[4];
  const float* W_dec    = (const float*)d_in[5];
  const float* b_dec    = (const float*)d_in[6];
  float* out = (float*)d_out;

  char* ws = (char*)d_ws;
  __hip_bfloat16* hs_bf   = (__hip_bfloat16*)(ws);                    // 1 MB
  __hip_bfloat16* WlatT   = (__hip_bfloat16*)(ws + (1u << 20));       // 2 MB
  unsigned char*  latent8 = (unsigned char*)(ws + 3u * (1u << 20));   // 2 MB [4096][512]
  unsigned char*  WdecT8  = (unsigned char*)(ws + 5u * (1u << 20));   // 16.4 MB [32000][512]
  float* log_coef = (float*)(ws + 22u * (1u << 20));                  // 16 KB
  float* S = log_coef + AROWS;                                        // 16 KB
  float* q = S + AROWS;                                               // 16 KB
  unsigned int* pbuf = (unsigned int*)(ws + 23u * (1u << 20));        // 131 MB

  const size_t needA = 23u * (1u << 20) + (size_t)L_ * V_ * 4;
  const bool pathA = ws_size >= needA;

  prep_kernel<<<PREP_TOT, 256, 0, stream>>>(hs, W_prior, b_prior, W_latent, W_dec,
                                            hs_bf, WlatT, WdecT8, log_coef, S);
  latent_gemm<<<dim3((E_ * D_) / 128, L_ / 128), 256, 0, stream>>>(hs_bf, WlatT, b_latent, latent8);

  if (pathA) {
    mos_gemm<3><<<8 * 16 * 63, 256, 0, stream>>>(latent8, WdecT8, b_dec, nullptr, S, nullptr, pbuf);
    combine_kernel<<<dim3(8, L_), 256, 0, stream>>>(pbuf, log_coef, S, out);
  } else {
    mos_gemm<1><<<8 * 16 * 63, 256, 0, stream>>>(latent8, WdecT8, b_dec, nullptr, S, nullptr, nullptr);
    qk_kernel<<<(AROWS + 255) / 256, 256, 0, stream>>>(log_coef, S, q);
    mos_gemm<2><<<8 * 16 * 63, 256, 0, stream>>>(latent8, WdecT8, b_dec, q, nullptr, out, nullptr);
  }
}